// Round 2
// baseline (215.380 us; speedup 1.0000x reference)
//
#include <hip/hip_runtime.h>
#include <hip/hip_bf16.h>

// SelfAttention_v2: Q=x@Wq^T, K=x@Wk^T, S=Q@K^T, causal softmax (post-softmax
// mask + renorm == causal softmax), exact JAX threefry dropout p=0.5 using the
// PARTITIONABLE threefry scheme (jax_threefry_partitionable=True default):
//   bits[i] = o1 ^ o2, (o1,o2) = threefry2x32(key=(0,123), x=(0, i))
//   keep    = !(bits >> 31)   [uniform < 0.5]
// Output: [4096,4096] f32 attention-weight matrix.

using bf16   = __bf16;
using bf16x8 = __attribute__((ext_vector_type(8))) __bf16;
using bf16x4 = __attribute__((ext_vector_type(4))) __bf16;
using f32x4  = __attribute__((ext_vector_type(4))) float;

constexpr int Tdim = 4096;
constexpr int Ddim = 1024;

// ---------------- cast f32 -> bf16 (RNE via compiler), x4 vectorized ----------------
__global__ __launch_bounds__(256) void k_cast_bf16(const float* __restrict__ in,
                                                   bf16* __restrict__ out, int n4) {
  int i = blockIdx.x * 256 + threadIdx.x;
  if (i >= n4) return;
  f32x4 v = reinterpret_cast<const f32x4*>(in)[i];
  bf16x4 o;
  o[0] = (bf16)v[0]; o[1] = (bf16)v[1]; o[2] = (bf16)v[2]; o[3] = (bf16)v[3];
  reinterpret_cast<bf16x4*>(out)[i] = o;
}

// ---------------- bf16 GEMM, C[m,n] = sum_k A[m,k]*B[n,k] ----------------
// A: M x K row-major bf16, B: N x K row-major bf16 (both K-contiguous).
// 128x128 tile, BK=32, 4 waves (2x2), each wave 64x64 = 4x4 mfma 16x16x32 frags.
// m97 structure: global_load_lds width-16 staging, 2 barriers per K-step.
template<int OUTF32>
__global__ __launch_bounds__(256)
void k_gemm_bt(const bf16* __restrict__ A, const bf16* __restrict__ B,
               void* __restrict__ Cv, int M, int N, int K, int causal) {
  const int nbn = N >> 7;
  const int bm = blockIdx.x / nbn;
  const int bn = blockIdx.x - bm * nbn;
  if (causal && bn > bm) return;  // fully-masked output block

  __shared__ __align__(16) bf16 As[128 * 32];
  __shared__ __align__(16) bf16 Bs[128 * 32];

  const int tid  = threadIdx.x;
  const int lane = tid & 63;
  const int wid  = tid >> 6;            // 0..3
  const int wr   = (wid >> 1) * 64;     // wave row offset in tile
  const int wc   = (wid & 1) * 64;      // wave col offset in tile
  const int fr   = lane & 15;           // fragment row/col within 16
  const int ko   = (lane >> 4) * 8;     // k offset within 32

  f32x4 acc[4][4];
#pragma unroll
  for (int i = 0; i < 4; ++i)
#pragma unroll
    for (int j = 0; j < 4; ++j) acc[i][j] = (f32x4){0.f, 0.f, 0.f, 0.f};

  const bf16* Ag = A + (long)bm * 128 * K;
  const bf16* Bg = B + (long)bn * 128 * K;

  // staging: thread covers 16B; row = i*64 + tid/4, colElem = (tid%4)*8
  const int srow0 = tid >> 2;
  const int scol  = (tid & 3) * 8;

  for (int kt = 0; kt < K; kt += 32) {
#pragma unroll
    for (int i = 0; i < 2; ++i) {
      const int row = i * 64 + srow0;
      const int ldsbase = (i * 256 + wid * 64) * 8;  // wave-uniform dest (elems)
      __builtin_amdgcn_global_load_lds(
          (const __attribute__((address_space(1))) void*)(Ag + (long)row * K + kt + scol),
          (__attribute__((address_space(3))) void*)(As + ldsbase), 16, 0, 0);
      __builtin_amdgcn_global_load_lds(
          (const __attribute__((address_space(1))) void*)(Bg + (long)row * K + kt + scol),
          (__attribute__((address_space(3))) void*)(Bs + ldsbase), 16, 0, 0);
    }
    __syncthreads();  // drains vmcnt before LDS reads

    bf16x8 av[4], bv[4];
#pragma unroll
    for (int f = 0; f < 4; ++f) {
      av[f] = *reinterpret_cast<const bf16x8*>(&As[(wr + f * 16 + fr) * 32 + ko]);
      bv[f] = *reinterpret_cast<const bf16x8*>(&Bs[(wc + f * 16 + fr) * 32 + ko]);
    }
#pragma unroll
    for (int fm = 0; fm < 4; ++fm)
#pragma unroll
      for (int fn = 0; fn < 4; ++fn)
        acc[fm][fn] = __builtin_amdgcn_mfma_f32_16x16x32_bf16(av[fm], bv[fn], acc[fm][fn], 0, 0, 0);
    __syncthreads();  // protect LDS before next stage
  }

  // epilogue: C/D layout col=lane&15, row=(lane>>4)*4+reg (m89/m91-verified)
  const int crow0 = (lane >> 4) * 4;
  const int ccol  = lane & 15;
#pragma unroll
  for (int fm = 0; fm < 4; ++fm)
#pragma unroll
    for (int fn = 0; fn < 4; ++fn)
#pragma unroll
      for (int j = 0; j < 4; ++j) {
        const long row = (long)bm * 128 + wr + fm * 16 + crow0 + j;
        const long col = (long)bn * 128 + wc + fn * 16 + ccol;
        const float v = acc[fm][fn][j];
        if (OUTF32) ((float*)Cv)[row * N + col] = v;
        else        ((bf16*)Cv)[row * N + col] = (bf16)v;
      }
}

// ---------------- JAX threefry2x32, key = jax.random.key(123) -> (0,123) ----------------
__device__ __forceinline__ unsigned rotl32(unsigned v, int d) {
  return (v << d) | (v >> (32 - d));
}
__device__ __forceinline__ void threefry_123(unsigned x0, unsigned x1,
                                             unsigned& o0, unsigned& o1) {
  const unsigned ks0 = 0u, ks1 = 123u;
  const unsigned ks2 = 0x1BD11BDAu ^ ks0 ^ ks1;
  x0 += ks0; x1 += ks1;
#define TF_R4(a, b, c, d)                                   \
  x0 += x1; x1 = rotl32(x1, a); x1 ^= x0;                   \
  x0 += x1; x1 = rotl32(x1, b); x1 ^= x0;                   \
  x0 += x1; x1 = rotl32(x1, c); x1 ^= x0;                   \
  x0 += x1; x1 = rotl32(x1, d); x1 ^= x0;
  TF_R4(13, 15, 26, 6);  x0 += ks1; x1 += ks2 + 1u;
  TF_R4(17, 29, 16, 24); x0 += ks2; x1 += ks0 + 2u;
  TF_R4(13, 15, 26, 6);  x0 += ks0; x1 += ks1 + 3u;
  TF_R4(17, 29, 16, 24); x0 += ks1; x1 += ks2 + 4u;
  TF_R4(13, 15, 26, 6);  x0 += ks2; x1 += ks0 + 5u;
#undef TF_R4
  o0 = x0; o1 = x1;
}

// keep bit for flat element i (partitionable scheme): counter = (hi=0, lo=i)
__device__ __forceinline__ bool keep_bit(unsigned i) {
  unsigned o0, o1;
  threefry_123(0u, i, o0, o1);
  return ((o0 ^ o1) & 0x80000000u) == 0u;
}

// ---------------- fused in-place causal softmax + dropout ----------------
// Block b handles rows r0=b (short) and r1=b+2048 (long) for load balance.
__global__ __launch_bounds__(256) void k_softmax_drop(float* __restrict__ S) {
  const int b  = blockIdx.x;
  const int r0 = b, r1 = b + (Tdim / 2);
  const int tid = threadIdx.x;
  __shared__ float redA[4], redB[4];

  float v0[8], v1[16];
  float lm0 = -3.0e38f, lm1 = -3.0e38f;
#pragma unroll
  for (int i = 0; i < 8; ++i) {
    const int c = tid + i * 256;
    v0[i] = (c <= r0) ? S[(long)r0 * Tdim + c] : -3.0e38f;
    lm0 = fmaxf(lm0, v0[i]);
  }
#pragma unroll
  for (int i = 0; i < 16; ++i) {
    const int c = tid + i * 256;
    v1[i] = (c <= r1) ? S[(long)r1 * Tdim + c] : -3.0e38f;
    lm1 = fmaxf(lm1, v1[i]);
  }
#pragma unroll
  for (int o = 32; o; o >>= 1) {
    lm0 = fmaxf(lm0, __shfl_xor(lm0, o));
    lm1 = fmaxf(lm1, __shfl_xor(lm1, o));
  }
  if ((tid & 63) == 0) { redA[tid >> 6] = lm0; redB[tid >> 6] = lm1; }
  __syncthreads();
  const float m0 = fmaxf(fmaxf(redA[0], redA[1]), fmaxf(redA[2], redA[3]));
  const float m1 = fmaxf(fmaxf(redB[0], redB[1]), fmaxf(redB[2], redB[3]));
  __syncthreads();

  constexpr float SC = 1.0f / 32.0f;  // 1/sqrt(1024)
  float ls0 = 0.f, ls1 = 0.f;
#pragma unroll
  for (int i = 0; i < 8; ++i) {
    const int c = tid + i * 256;
    const float e = (c <= r0) ? __expf((v0[i] - m0) * SC) : 0.f;
    v0[i] = e; ls0 += e;
  }
#pragma unroll
  for (int i = 0; i < 16; ++i) {
    const int c = tid + i * 256;
    const float e = (c <= r1) ? __expf((v1[i] - m1) * SC) : 0.f;
    v1[i] = e; ls1 += e;
  }
#pragma unroll
  for (int o = 32; o; o >>= 1) { ls0 += __shfl_xor(ls0, o); ls1 += __shfl_xor(ls1, o); }
  if ((tid & 63) == 0) { redA[tid >> 6] = ls0; redB[tid >> 6] = ls1; }
  __syncthreads();
  const float inv0 = 2.0f / (redA[0] + redA[1] + redA[2] + redA[3]);  // /0.5 dropout scale
  const float inv1 = 2.0f / (redB[0] + redB[1] + redB[2] + redB[3]);

  // dropout: per-element partitionable threefry. Row r0 elements at c>=2048
  // are always causally masked -> no PRNG eval needed (write 0).
#pragma unroll
  for (int i = 0; i < 16; ++i) {
    const int c = tid + i * 256;
    const unsigned j = (unsigned)(r0 * Tdim + c);  // flat idx for (r0,c)
    float o1v = 0.f;
    if (c <= r1 && keep_bit(j + 8388608u)) o1v = v1[i] * inv1;  // (r1,c) = j + 2^23
    S[(long)r1 * Tdim + c] = o1v;
    float o0v = 0.f;
    if (i < 8 && c <= r0 && keep_bit(j)) o0v = v0[i & 7] * inv0;
    S[(long)r0 * Tdim + c] = o0v;
  }
}

extern "C" void kernel_launch(void* const* d_in, const int* in_sizes, int n_in,
                              void* d_out, int out_size, void* d_ws, size_t ws_size,
                              hipStream_t stream) {
  const float* x  = (const float*)d_in[0];
  const float* Wq = (const float*)d_in[1];
  const float* Wk = (const float*)d_in[2];
  // d_in[3] (W_value) feeds only dead code in the reference — unused.
  float* S  = (float*)d_out;
  char* ws  = (char*)d_ws;
  bf16* xb  = (bf16*)(ws);                 //  8 MB: x bf16 [4096,1024]
  bf16* wqb = (bf16*)(ws + (8l  << 20));   //  2 MB
  bf16* wkb = (bf16*)(ws + (10l << 20));   //  2 MB
  bf16* Qb  = (bf16*)(ws + (12l << 20));   //  8 MB: Q bf16
  bf16* Kb  = (bf16*)(ws + (20l << 20));   //  8 MB: K bf16  (total 28 MB)

  k_cast_bf16<<<(Tdim * Ddim / 4) / 256, 256, 0, stream>>>(x,  xb,  Tdim * Ddim / 4);
  k_cast_bf16<<<(Ddim * Ddim / 4) / 256, 256, 0, stream>>>(Wq, wqb, Ddim * Ddim / 4);
  k_cast_bf16<<<(Ddim * Ddim / 4) / 256, 256, 0, stream>>>(Wk, wkb, Ddim * Ddim / 4);

  k_gemm_bt<0><<<(Tdim / 128) * (Ddim / 128), 256, 0, stream>>>(xb, wqb, Qb, Tdim, Ddim, Ddim, 0);
  k_gemm_bt<0><<<(Tdim / 128) * (Ddim / 128), 256, 0, stream>>>(xb, wkb, Kb, Tdim, Ddim, Ddim, 0);
  k_gemm_bt<1><<<(Tdim / 128) * (Tdim / 128), 256, 0, stream>>>(Qb, Kb, (void*)S, Tdim, Tdim, Ddim, 1);

  k_softmax_drop<<<Tdim / 2, 256, 0, stream>>>(S);
}

// Round 3
// 193.669 us; speedup vs baseline: 1.1121x; 1.1121x over previous
//
#include <hip/hip_runtime.h>
#include <hip/hip_bf16.h>

// SelfAttention_v2: S = x·(Wq^T·Wk)·x^T (algebraic rewrite saves one big GEMM),
// causal softmax (post-softmax mask+renorm == causal softmax), exact JAX
// partitionable-threefry dropout p=0.5 (verified round 2).
// GEMMs use T3-min 2-phase double-buffered LDS (stage-next overlaps compute).

using bf16   = __bf16;
using bf16x8 = __attribute__((ext_vector_type(8))) __bf16;
using bf16x4 = __attribute__((ext_vector_type(4))) __bf16;
using f32x4  = __attribute__((ext_vector_type(4))) float;

constexpr int Tdim = 4096;
constexpr int Ddim = 1024;

// ---------------- cast f32 -> bf16, x4 vectorized ----------------
__global__ __launch_bounds__(256) void k_cast_bf16(const float* __restrict__ in,
                                                   bf16* __restrict__ out, int n4) {
  int i = blockIdx.x * 256 + threadIdx.x;
  if (i >= n4) return;
  f32x4 v = reinterpret_cast<const f32x4*>(in)[i];
  bf16x4 o;
  o[0] = (bf16)v[0]; o[1] = (bf16)v[1]; o[2] = (bf16)v[2]; o[3] = (bf16)v[3];
  reinterpret_cast<bf16x4*>(out)[i] = o;
}

// ---------------- fused transpose+cast for Wq,Wk (1024x1024 f32 -> bf16^T) ----
__global__ __launch_bounds__(256) void k_tcast(const float* __restrict__ q,
                                               const float* __restrict__ k,
                                               bf16* __restrict__ qt,
                                               bf16* __restrict__ kt) {
  const float* in = blockIdx.z ? k : q;
  bf16* out = blockIdx.z ? kt : qt;
  __shared__ float t[32][33];
  const int tx = threadIdx.x & 31;
  const int ty = threadIdx.x >> 5;  // 0..7
  const int r0 = blockIdx.y * 32;
  const int c0 = blockIdx.x * 32;
#pragma unroll
  for (int r = 0; r < 4; ++r)
    t[ty * 4 + r][tx] = in[(r0 + ty * 4 + r) * Ddim + c0 + tx];
  __syncthreads();
#pragma unroll
  for (int r = 0; r < 4; ++r)
    out[(c0 + ty * 4 + r) * Ddim + r0 + tx] = (bf16)t[tx][ty * 4 + r];
}

// ---------------- reduce 4 split-K partials + cast to bf16 ----------------
__global__ __launch_bounds__(256) void k_redcast(const float* __restrict__ p,
                                                 bf16* __restrict__ g) {
  const int i = blockIdx.x * 256 + threadIdx.x;  // < 1M/4
  f32x4 a = reinterpret_cast<const f32x4*>(p)[i];
  f32x4 b = reinterpret_cast<const f32x4*>(p + (1 << 20))[i];
  f32x4 c = reinterpret_cast<const f32x4*>(p + (2 << 20))[i];
  f32x4 d = reinterpret_cast<const f32x4*>(p + (3 << 20))[i];
  f32x4 s = a + b + c + d;
  bf16x4 o;
  o[0] = (bf16)s[0]; o[1] = (bf16)s[1]; o[2] = (bf16)s[2]; o[3] = (bf16)s[3];
  reinterpret_cast<bf16x4*>(g)[i] = o;
}

__device__ __forceinline__ void gll16(const bf16* g, bf16* l) {
  __builtin_amdgcn_global_load_lds(
      (const __attribute__((address_space(1))) void*)g,
      (__attribute__((address_space(3))) void*)l, 16, 0, 0);
}

// ---------------- bf16 GEMM, C[m,n] = sum_k A[m,k]*B[n,k] ----------------
// 128x128 tile, BK=32, 4 waves (2x2), 4x4 16x16x32 frags/wave.
// T3-min 2-phase: double-buffered LDS, stage(next) issued before compute(cur),
// single __syncthreads per K-tile (vmcnt drain overlapped with MFMA).
// blockIdx.y = split-K chunk: K-range [y*kLen, (y+1)*kLen), C += y*cZs (f32 out).
template<int OUTF32>
__global__ __launch_bounds__(256)
void k_gemm_bt(const bf16* __restrict__ A, const bf16* __restrict__ B,
               void* __restrict__ Cv, int N, int lda, int ldb, int kLen,
               long cZs, int causal) {
  const int nbn = N >> 7;
  const int bm = blockIdx.x / nbn;
  const int bn = blockIdx.x - bm * nbn;
  if (causal && bn > bm) return;  // fully-masked output block

  __shared__ __align__(16) bf16 As[2][128 * 32];
  __shared__ __align__(16) bf16 Bs[2][128 * 32];

  const int tid  = threadIdx.x;
  const int lane = tid & 63;
  const int wid  = tid >> 6;
  const int wr   = (wid >> 1) * 64;
  const int wc   = (wid & 1) * 64;
  const int fr   = lane & 15;
  const int ko   = (lane >> 4) * 8;

  f32x4 acc[4][4];
#pragma unroll
  for (int i = 0; i < 4; ++i)
#pragma unroll
    for (int j = 0; j < 4; ++j) acc[i][j] = (f32x4){0.f, 0.f, 0.f, 0.f};

  const bf16* Ag = A + (long)bm * 128 * lda;
  const bf16* Bg = B + (long)bn * 128 * ldb;
  const int srow0 = tid >> 2;
  const int scol  = (tid & 3) * 8;
  const int k0 = blockIdx.y * kLen;

  auto stage = [&](int buf, int kt) {
#pragma unroll
    for (int i = 0; i < 2; ++i) {
      const int row = i * 64 + srow0;
      const int lb  = (i * 256 + wid * 64) * 8;  // wave-uniform dest
      gll16(Ag + (long)row * lda + kt + scol, &As[buf][lb]);
      gll16(Bg + (long)row * ldb + kt + scol, &Bs[buf][lb]);
    }
  };
  auto compute = [&](int buf) {
    bf16x8 av[4], bv[4];
#pragma unroll
    for (int f = 0; f < 4; ++f) {
      av[f] = *reinterpret_cast<const bf16x8*>(&As[buf][(wr + f * 16 + fr) * 32 + ko]);
      bv[f] = *reinterpret_cast<const bf16x8*>(&Bs[buf][(wc + f * 16 + fr) * 32 + ko]);
    }
#pragma unroll
    for (int fm = 0; fm < 4; ++fm)
#pragma unroll
      for (int fn = 0; fn < 4; ++fn)
        acc[fm][fn] = __builtin_amdgcn_mfma_f32_16x16x32_bf16(av[fm], bv[fn], acc[fm][fn], 0, 0, 0);
  };

  stage(0, k0);
  __syncthreads();
  int cur = 0;
  for (int kt = 32; kt < kLen; kt += 32) {
    stage(cur ^ 1, k0 + kt);  // issue next tile's loads (other buffer)
    compute(cur);             // overlaps load latency
    __syncthreads();          // next buffer ready; cur reads done
    cur ^= 1;
  }
  compute(cur);  // last tile

  // epilogue: C/D layout col=lane&15, row=(lane>>4)*4+reg (m89/m91-verified)
  const int crow0 = (lane >> 4) * 4;
  const int ccol  = lane & 15;
#pragma unroll
  for (int fm = 0; fm < 4; ++fm)
#pragma unroll
    for (int fn = 0; fn < 4; ++fn)
#pragma unroll
      for (int j = 0; j < 4; ++j) {
        const long row = (long)bm * 128 + wr + fm * 16 + crow0 + j;
        const long col = (long)bn * 128 + wc + fn * 16 + ccol;
        const float v = acc[fm][fn][j];
        if (OUTF32) ((float*)Cv + (long)blockIdx.y * cZs)[row * N + col] = v;
        else        ((bf16*)Cv)[row * N + col] = (bf16)v;
      }
}

// ---------------- JAX threefry2x32, key = (0,123) ----------------
__device__ __forceinline__ unsigned rotl32(unsigned v, int d) {
  return (v << d) | (v >> (32 - d));
}
__device__ __forceinline__ void threefry_123(unsigned x0, unsigned x1,
                                             unsigned& o0, unsigned& o1) {
  const unsigned ks0 = 0u, ks1 = 123u;
  const unsigned ks2 = 0x1BD11BDAu ^ ks0 ^ ks1;
  x0 += ks0; x1 += ks1;
#define TF_R4(a, b, c, d)                                   \
  x0 += x1; x1 = rotl32(x1, a); x1 ^= x0;                   \
  x0 += x1; x1 = rotl32(x1, b); x1 ^= x0;                   \
  x0 += x1; x1 = rotl32(x1, c); x1 ^= x0;                   \
  x0 += x1; x1 = rotl32(x1, d); x1 ^= x0;
  TF_R4(13, 15, 26, 6);  x0 += ks1; x1 += ks2 + 1u;
  TF_R4(17, 29, 16, 24); x0 += ks2; x1 += ks0 + 2u;
  TF_R4(13, 15, 26, 6);  x0 += ks0; x1 += ks1 + 3u;
  TF_R4(17, 29, 16, 24); x0 += ks1; x1 += ks2 + 4u;
  TF_R4(13, 15, 26, 6);  x0 += ks2; x1 += ks0 + 5u;
#undef TF_R4
  o0 = x0; o1 = x1;
}
// partitionable scheme: bits = o0^o1, counter (0, i); keep = top bit clear
__device__ __forceinline__ bool keep_bit(unsigned i) {
  unsigned o0, o1;
  threefry_123(0u, i, o0, o1);
  return ((o0 ^ o1) & 0x80000000u) == 0u;
}

// ---------------- fused in-place causal softmax + dropout ----------------
__global__ __launch_bounds__(256) void k_softmax_drop(float* __restrict__ S) {
  const int b  = blockIdx.x;
  const int r0 = b, r1 = b + (Tdim / 2);
  const int tid = threadIdx.x;
  __shared__ float redA[4], redB[4];

  float v0[8], v1[16];
  float lm0 = -3.0e38f, lm1 = -3.0e38f;
#pragma unroll
  for (int i = 0; i < 8; ++i) {
    const int c = tid + i * 256;
    v0[i] = (c <= r0) ? S[(long)r0 * Tdim + c] : -3.0e38f;
    lm0 = fmaxf(lm0, v0[i]);
  }
#pragma unroll
  for (int i = 0; i < 16; ++i) {
    const int c = tid + i * 256;
    v1[i] = (c <= r1) ? S[(long)r1 * Tdim + c] : -3.0e38f;
    lm1 = fmaxf(lm1, v1[i]);
  }
#pragma unroll
  for (int o = 32; o; o >>= 1) {
    lm0 = fmaxf(lm0, __shfl_xor(lm0, o));
    lm1 = fmaxf(lm1, __shfl_xor(lm1, o));
  }
  if ((tid & 63) == 0) { redA[tid >> 6] = lm0; redB[tid >> 6] = lm1; }
  __syncthreads();
  const float m0 = fmaxf(fmaxf(redA[0], redA[1]), fmaxf(redA[2], redA[3]));
  const float m1 = fmaxf(fmaxf(redB[0], redB[1]), fmaxf(redB[2], redB[3]));
  __syncthreads();

  constexpr float SC = 1.0f / 32.0f;  // 1/sqrt(1024)
  float ls0 = 0.f, ls1 = 0.f;
#pragma unroll
  for (int i = 0; i < 8; ++i) {
    const int c = tid + i * 256;
    const float e = (c <= r0) ? __expf((v0[i] - m0) * SC) : 0.f;
    v0[i] = e; ls0 += e;
  }
#pragma unroll
  for (int i = 0; i < 16; ++i) {
    const int c = tid + i * 256;
    const float e = (c <= r1) ? __expf((v1[i] - m1) * SC) : 0.f;
    v1[i] = e; ls1 += e;
  }
#pragma unroll
  for (int o = 32; o; o >>= 1) { ls0 += __shfl_xor(ls0, o); ls1 += __shfl_xor(ls1, o); }
  if ((tid & 63) == 0) { redA[tid >> 6] = ls0; redB[tid >> 6] = ls1; }
  __syncthreads();
  const float inv0 = 2.0f / (redA[0] + redA[1] + redA[2] + redA[3]);
  const float inv1 = 2.0f / (redB[0] + redB[1] + redB[2] + redB[3]);

#pragma unroll
  for (int i = 0; i < 16; ++i) {
    const int c = tid + i * 256;
    const unsigned j = (unsigned)(r0 * Tdim + c);
    float o1v = 0.f;
    if (c <= r1 && keep_bit(j + 8388608u)) o1v = v1[i] * inv1;
    S[(long)r1 * Tdim + c] = o1v;
    float o0v = 0.f;
    if (i < 8 && c <= r0 && keep_bit(j)) o0v = v0[i & 7] * inv0;
    S[(long)r0 * Tdim + c] = o0v;
  }
}

extern "C" void kernel_launch(void* const* d_in, const int* in_sizes, int n_in,
                              void* d_out, int out_size, void* d_ws, size_t ws_size,
                              hipStream_t stream) {
  const float* x  = (const float*)d_in[0];
  const float* Wq = (const float*)d_in[1];
  const float* Wk = (const float*)d_in[2];
  // d_in[3] (W_value) feeds only dead code in the reference — unused.
  float* S = (float*)d_out;
  char* ws = (char*)d_ws;
  bf16*  xb = (bf16*)(ws);                  //  8 MB: x bf16 [4096,1024]
  bf16*  qt = (bf16*)(ws + (8l  << 20));    //  2 MB: Wq^T bf16
  bf16*  kt = (bf16*)(ws + (10l << 20));    //  2 MB: Wk^T bf16
  float* Wp = (float*)(ws + (12l << 20));   // 16 MB: 4 split-K partials of G
  bf16*  G  = (bf16*)(ws + (28l << 20));    //  2 MB: G = Wk^T·Wq  (= (Wq^T·Wk)^T)
  bf16*  P  = (bf16*)(ws + (30l << 20));    //  8 MB: P = x·(Wq^T·Wk)   (38 MB total)

  k_cast_bf16<<<(Tdim * Ddim / 4) / 256, 256, 0, stream>>>(x, xb, Tdim * Ddim / 4);
  k_tcast<<<dim3(32, 32, 2), 256, 0, stream>>>(Wq, Wk, qt, kt);

  // G partials: G[i,j] = sum_k Wk[k,i]*Wq[k,j], split-K=4 (grid.y)
  k_gemm_bt<1><<<dim3(64, 4), 256, 0, stream>>>(kt, qt, (void*)Wp, Ddim, Ddim, Ddim,
                                                Ddim / 4, 1l << 20, 0);
  k_redcast<<<(Ddim * Ddim / 4) / 256, 256, 0, stream>>>(Wp, G);

  // P[m,n] = sum_k x[m,k]*G[n,k] = (x · Wq^T·Wk)[m,n]
  k_gemm_bt<0><<<dim3((Tdim / 128) * (Ddim / 128), 1), 256, 0, stream>>>(
      xb, G, (void*)P, Ddim, Ddim, Ddim, Ddim, 0, 0);
  // S[m,n] = sum_k P[m,k]*x[n,k] = (x·Wq^T·Wk·x^T)[m,n], causal blocks only
  k_gemm_bt<1><<<dim3((Tdim / 128) * (Tdim / 128), 1), 256, 0, stream>>>(
      P, xb, (void*)S, Tdim, Ddim, Ddim, Ddim, 0, 1);

  k_softmax_drop<<<Tdim / 2, 256, 0, stream>>>(S);
}